// Round 5
// baseline (13530.211 us; speedup 1.0000x reference)
//
#include <hip/hip_runtime.h>

#define TT 128
#define BB 64
#define HH 1024
#define LL 4
#define NSL 128            // 8-hidden-unit slices per layer
#define NWG (LL * NSL)     // 512 workgroups
#define NPROD 128u         // producers per (layer, t) flag

typedef _Float16 f16;
typedef __attribute__((ext_vector_type(4))) _Float16 f16x4;
typedef __attribute__((ext_vector_type(8))) _Float16 f16x8;
typedef __attribute__((ext_vector_type(4))) float f32x4;

// ---------------- persistent device buffers ----------------
// Fragment layout for a [64 rows x 1024 k] fp16 tensor (HW-verified r1/r4):
//   flat = ((rg*32 + ktp)*64 + lane)*8 + e
//   rg = row>>4, ktp = k>>5, lane = ((k>>2)&3)<<4 | (row&15), e = ((k>>4)&1)<<2 | (k&3)
// A-frag for v_mfma_f32_16x16x16f16: m = lane&15, k = 4*(lane>>4)+e
__device__ __align__(16) f16 g_in16[TT][65536];           // inputs, frag layout per t
// write-once state slots: slot t+1 holds post-step-t state.
__device__ __align__(16) f16 g_c16[LL][TT + 1][65536];    // cell state fp16 (feeds next layer)
__device__ __align__(16) f16 g_h16[LL][TT + 1][65536];    // hidden state fp16 (U-matmul input)
__device__ __align__(16) float g_c32[LL][BB][HH];         // cell state master f32 (WG-private)
__device__ unsigned g_done[LL][TT];                       // completion counters (128 WGs each)

// ---------------- init: zero state slot 0 + flags + c32 ----------------
__global__ void k_init() {
  unsigned tid = blockIdx.x * blockDim.x + threadIdx.x;
  unsigned n = gridDim.x * blockDim.x;
  float* c32 = &g_c32[0][0][0];
  for (unsigned i = tid; i < LL * BB * HH; i += n) c32[i] = 0.f;
  for (unsigned i = tid; i < LL * 65536 / 2; i += n) {
    int jj = i >> 15, q = i & 32767;
    ((unsigned*)&g_h16[jj][0][0])[q] = 0u;
  }
  unsigned* pd = &g_done[0][0];
  for (unsigned i = tid; i < LL * TT; i += n) pd[i] = 0u;
}

// ---------------- pack inputs f32 -> fp16 fragment layout (verified) ----------------
__global__ void k_pack_in(const float* __restrict__ inp) {
  int tid = blockIdx.x * blockDim.x + threadIdx.x;
  int t = tid >> 14, q = tid & 16383;
  int row = q >> 8, hu = (q & 255) << 2;
  const float4 x = *(const float4*)(inp + ((size_t)t << 16) + (row << 10) + hu);
  int rg = row >> 4, ktp = hu >> 5;
  int ln = (((hu >> 2) & 3) << 4) | (row & 15);
  int e0 = ((hu >> 4) & 1) << 2;
  f16x4 v = {(f16)x.x, (f16)x.y, (f16)x.z, (f16)x.w};
  *(f16x4*)&g_in16[t][(((rg * 32 + ktp) * 64 + ln) << 3) + e0] = v;
}

// ---------------- main persistent kernel ----------------
__device__ __forceinline__ float sigf(float x) { return 1.f / (1.f + __expf(-x)); }
__device__ __forceinline__ float tanh_(float x) {
  float q = __expf(-2.f * fabsf(x));
  return copysignf((1.f - q) / (1.f + q), x);
}
__device__ __forceinline__ f16x4 lo8(f16x8 v) { return __builtin_shufflevector(v, v, 0, 1, 2, 3); }
__device__ __forceinline__ f16x4 hi8(f16x8 v) { return __builtin_shufflevector(v, v, 4, 5, 6, 7); }
__device__ __forceinline__ void waitflag(const unsigned* p, unsigned n) {
  while (__hip_atomic_load(p, __ATOMIC_RELAXED, __HIP_MEMORY_SCOPE_AGENT) < n)
    __builtin_amdgcn_s_sleep(2);
}

#define MFMA16(A_, B_, C_) __builtin_amdgcn_mfma_f32_16x16x16f16(A_, B_, C_, 0, 0, 0)
// zl column swizzle: spreads epilogue float2 gathers across all 32 banks (b64 floor)
#define SWZ(r) ((((r) & 4) << 2) ^ (((r) & 3) << 3))

// Decomposition: WG (j,s) owns 64 rows x 32 gate-cols (8 hidden units x 4 gates).
// Wave w: mat = w>>2 (0: x@W, 1: h@U), K-quarter kq = w&3 -> holds B-frags for its
// 32 cols x 256 K in 16 f16x8 = 64 VGPRs (fits: no spill, unlike r4's 128).
// Tile col c = gate*8 + hu_local; MFMA n-index = (gate&1)*8 + hul, cf = gate>>1.
// Sync: r4-proven protocol (tid0 waits + agent acquire fence + barrier;
// release fence + vmcnt drain + barrier + flag bump).
__global__ __launch_bounds__(512, 2) void k_main(const float* __restrict__ W,
                                                 const float* __restrict__ U,
                                                 const float* __restrict__ bias,
                                                 float* __restrict__ out) {
  const int j = blockIdx.x >> 7, s = blockIdx.x & 127;
  const int tid = threadIdx.x, lane = tid & 63, wv = tid >> 6;
  const int mat = wv >> 2, kq = wv & 3;
  __shared__ float zl[16384];  // [8 waves][64 rows][32 cols], swizzled, 64 KiB

  // ---- one-time weight gather f32 -> fp16 regs ----
  // Wr[kc*2+hf] lo half = cf0 (gates 0-1), hi half = cf1 (gates 2-3);
  // element e: k = kq*256 + (kc*2+hf)*16 + ((lane>>4)<<2) + e,
  // col = (cfh*2 + ((lane>>3)&1))*1024 + s*8 + (lane&7).
  const float* src = (mat ? U : W) + (size_t)j * (HH * 4 * HH);
  const int kb0 = kq * 256 + ((lane >> 4) << 2);
  const int cb0 = s * 8 + (lane & 7) + ((lane >> 3) & 1) * 1024;
  f16x8 Wr[16];
#pragma unroll
  for (int kk = 0; kk < 16; ++kk) {
    f16x8 v;
#pragma unroll
    for (int cfh = 0; cfh < 2; ++cfh)
#pragma unroll
      for (int e = 0; e < 4; ++e)
        v[cfh * 4 + e] = (f16)src[(size_t)(kb0 + kk * 16 + e) * 4096 + cfh * 2048 + cb0];
    Wr[kk] = v;
  }

  // ---- per-thread epilogue constants (threads 0..255 active) ----
  const bool act = tid < 256;
  const int row = (tid & 255) >> 2;   // 0..63
  const int hl0 = (tid & 3) * 2;      // 0,2,4,6
  const int hu0 = s * 8 + hl0;
  float br[2][4];
#pragma unroll
  for (int el = 0; el < 2; ++el)
#pragma unroll
    for (int g = 0; g < 4; ++g) br[el][g] = bias[j * 4096 + g * 1024 + hu0 + el];
  const int fibase = ((((row >> 4) * 32 + (hu0 >> 5)) * 64 +
                       ((((hu0 >> 2) & 3) << 4) | (row & 15))) << 3) +
                     ((((hu0 >> 4) & 1) << 2) | (hu0 & 3));
  const int fib2 = fibase >> 1;  // u32 index (fibase even: hu0 even)
  unsigned* const hPub = (unsigned*)&g_h16[j][0][0];
  unsigned* const cPub = (unsigned*)&g_c16[j][0][0];
  float* c32p = &g_c32[j][row][hu0];
  const int ktp0 = kq * 8;

  for (int t = 0; t < TT; ++t) {
    // ---- WG-level dependency wait + acquire (r4-proven) ----
    if (tid == 0) {
      if (j > 0) waitflag(&g_done[j - 1][t], NPROD);
      if (t > 0) waitflag(&g_done[j][t - 1], NPROD);
      __builtin_amdgcn_fence(__ATOMIC_ACQUIRE, "agent");
    }
    __syncthreads();

    const f16* Ab = mat ? &g_h16[j][t][0]
                        : (j ? &g_c16[j - 1][t + 1][0] : &g_in16[t][0]);
    f16x8 a[2][4];
#pragma unroll
    for (int rf = 0; rf < 4; ++rf)
      a[0][rf] = *(const f16x8*)(Ab + (rf * 32 + ktp0) * 512 + lane * 8);

    f32x4 acc[4][2];
#pragma unroll
    for (int rf = 0; rf < 4; ++rf)
#pragma unroll
      for (int cf = 0; cf < 2; ++cf) acc[rf][cf] = (f32x4){0.f, 0.f, 0.f, 0.f};

#pragma unroll
    for (int kc = 0; kc < 8; ++kc) {
      if (kc < 7) {
#pragma unroll
        for (int rf = 0; rf < 4; ++rf)
          a[(kc + 1) & 1][rf] = *(const f16x8*)(Ab + (rf * 32 + ktp0 + kc + 1) * 512 + lane * 8);
      }
#pragma unroll
      for (int hf = 0; hf < 2; ++hf) {
        const f16x8 wreg = Wr[kc * 2 + hf];
        const f16x4 b0 = lo8(wreg), b1 = hi8(wreg);
#pragma unroll
        for (int rf = 0; rf < 4; ++rf) {
          const f16x4 a4 = hf ? hi8(a[kc & 1][rf]) : lo8(a[kc & 1][rf]);
          acc[rf][0] = MFMA16(a4, b0, acc[rf][0]);
          acc[rf][1] = MFMA16(a4, b1, acc[rf][1]);
        }
      }
    }

    // ---- 8-wave reduction via 64 KiB LDS, single phase ----
    __syncthreads();  // zl reuse guard vs previous step's reads
#pragma unroll
    for (int rf = 0; rf < 4; ++rf)
#pragma unroll
      for (int cf = 0; cf < 2; ++cf)
#pragma unroll
        for (int ri = 0; ri < 4; ++ri) {
          const int rr = rf * 16 + ((lane >> 4) << 2) + ri;
          const int c2 = cf * 16 + (lane & 15);
          zl[wv * 2048 + rr * 32 + (c2 ^ SWZ(rr))] = acc[rf][cf][ri];
        }
    __syncthreads();

    if (act) {
      float gsum[2][4];
#pragma unroll
      for (int g = 0; g < 4; ++g) {
        const int idx = row * 32 + ((g * 8 + hl0) ^ SWZ(row));
        float sx = 0.f, sy = 0.f;
#pragma unroll
        for (int w = 0; w < 8; ++w) {
          const float2 v = *(const float2*)&zl[w * 2048 + idx];
          sx += v.x; sy += v.y;
        }
        gsum[0][g] = sx;
        gsum[1][g] = sy;
      }

      // ---- gates + state update (i,f,g,o) ----
      float cns[2], hns[2];
#pragma unroll
      for (int el = 0; el < 2; ++el) {
        const float zi = gsum[el][0] + br[el][0];
        const float zf = gsum[el][1] + br[el][1];
        const float zg = gsum[el][2] + br[el][2];
        const float zo = gsum[el][3] + br[el][3];
        const float cp = c32p[el];
        const float cn = sigf(zf) * cp + sigf(zi) * tanh_(zg);
        c32p[el] = cn;
        cns[el] = cn;
        hns[el] = sigf(zo) * tanh_(cn);
      }
      union { f16 h[2]; unsigned u; } ph, pc;
      ph.h[0] = (f16)hns[0]; ph.h[1] = (f16)hns[1];
      __hip_atomic_store(hPub + (size_t)(t + 1) * 32768 + fib2, ph.u,
                         __ATOMIC_RELAXED, __HIP_MEMORY_SCOPE_AGENT);
      if (j < 3) {
        pc.h[0] = (f16)cns[0]; pc.h[1] = (f16)cns[1];
        __hip_atomic_store(cPub + (size_t)(t + 1) * 32768 + fib2, pc.u,
                           __ATOMIC_RELAXED, __HIP_MEMORY_SCOPE_AGENT);
      }
      if (j == 3 && t == TT - 1) {
        out[(row << 10) + hu0] = cns[0];
        out[(row << 10) + hu0 + 1] = cns[1];
      }
    }

    // ---- release + completion flag (r4-proven) ----
    __builtin_amdgcn_fence(__ATOMIC_RELEASE, "agent");
    asm volatile("s_waitcnt vmcnt(0)" ::: "memory");
    __syncthreads();
    if (tid == 0)
      __hip_atomic_fetch_add(&g_done[j][t], 1u, __ATOMIC_RELAXED, __HIP_MEMORY_SCOPE_AGENT);
  }
}

extern "C" void kernel_launch(void* const* d_in, const int* in_sizes, int n_in,
                              void* d_out, int out_size, void* d_ws, size_t ws_size,
                              hipStream_t stream) {
  const float* inp  = (const float*)d_in[0];
  const float* W    = (const float*)d_in[1];
  const float* U    = (const float*)d_in[2];
  const float* bias = (const float*)d_in[3];
  float* out = (float*)d_out;
  k_init<<<256, 256, 0, stream>>>();
  k_pack_in<<<4096, 512, 0, stream>>>(inp);
  k_main<<<NWG, 512, 0, stream>>>(W, U, bias, out);
}

// Round 6
// 3653.444 us; speedup vs baseline: 3.7034x; 3.7034x over previous
//
#include <hip/hip_runtime.h>

#define TT 128
#define BB 64
#define HH 1024
#define LL 4
#define NWG 256
#define NPROD 64u

typedef _Float16 f16;
typedef __attribute__((ext_vector_type(4))) _Float16 f16x4;
typedef __attribute__((ext_vector_type(8))) _Float16 f16x8;
typedef __attribute__((ext_vector_type(4))) float f32x4;
typedef unsigned long long u64;

// ---------------- persistent device buffers ----------------
// Fragment layout for a [64 rows x 1024 k] fp16 tensor (HW-verified r1/r4):
//   flat = ((rg*32 + ktp)*64 + lane)*8 + e
//   rg = row>>4, ktp = k>>5, lane = ((k>>2)&3)<<4 | (row&15), e = ((k>>4)&1)<<2 | (k&3)
// A-frag for v_mfma_f32_16x16x16f16: m = lane&15, k = 4*(lane>>4)+e
__device__ __align__(16) f16 g_in16[TT][65536];           // inputs, frag layout per t
// write-once state slots: slot t+1 holds post-step-t state. Producers publish with
// device-scope atomic stores (write-through to MALL); consumers read with device-scope
// atomic loads (bypass possibly-stale L1/L2). NO cache-wide fences anywhere.
__device__ __align__(16) f16 g_c16[LL][TT + 1][65536];    // cell state fp16 (feeds next layer)
__device__ __align__(16) f16 g_h16[LL][TT + 1][65536];    // hidden state fp16 (U-matmul input)
__device__ __align__(16) float g_c32[LL][BB][HH];         // cell state master f32 (WG-private)
__device__ unsigned g_done[LL][TT];                       // completion counters (64 WGs each)

// ---------------- init: zero state slot 0 + flags + c32 ----------------
__global__ void k_init() {
  unsigned tid = blockIdx.x * blockDim.x + threadIdx.x;
  unsigned n = gridDim.x * blockDim.x;
  float* c32 = &g_c32[0][0][0];
  for (unsigned i = tid; i < LL * BB * HH; i += n) c32[i] = 0.f;
  for (unsigned i = tid; i < LL * 65536 / 2; i += n) {
    int jj = i >> 15, q = i & 32767;
    ((unsigned*)&g_h16[jj][0][0])[q] = 0u;
  }
  unsigned* pd = &g_done[0][0];
  for (unsigned i = tid; i < LL * TT; i += n) pd[i] = 0u;
}

// ---------------- pack inputs f32 -> fp16 fragment layout (verified) ----------------
__global__ void k_pack_in(const float* __restrict__ inp) {
  int tid = blockIdx.x * blockDim.x + threadIdx.x;
  int t = tid >> 14, q = tid & 16383;
  int row = q >> 8, hu = (q & 255) << 2;
  const float4 x = *(const float4*)(inp + ((size_t)t << 16) + (row << 10) + hu);
  int rg = row >> 4, ktp = hu >> 5;
  int ln = (((hu >> 2) & 3) << 4) | (row & 15);
  int e0 = ((hu >> 4) & 1) << 2;
  f16x4 v = {(f16)x.x, (f16)x.y, (f16)x.z, (f16)x.w};
  *(f16x4*)&g_in16[t][(((rg * 32 + ktp) * 64 + ln) << 3) + e0] = v;
}

// ---------------- main persistent kernel ----------------
__device__ __forceinline__ float sigf(float x) { return 1.f / (1.f + __expf(-x)); }
__device__ __forceinline__ float tanh_(float x) {
  float q = __expf(-2.f * fabsf(x));
  return copysignf((1.f - q) / (1.f + q), x);
}
__device__ __forceinline__ f16x4 lo8(f16x8 v) { return __builtin_shufflevector(v, v, 0, 1, 2, 3); }
__device__ __forceinline__ f16x4 hi8(f16x8 v) { return __builtin_shufflevector(v, v, 4, 5, 6, 7); }
__device__ __forceinline__ void waitflag(const unsigned* p, unsigned n) {
  while (__hip_atomic_load(p, __ATOMIC_RELAXED, __HIP_MEMORY_SCOPE_AGENT) < n)
    __builtin_amdgcn_s_sleep(2);
}
// coherent (device-scope) 16B state load: two u64 atomic loads, bypass stale L1/L2,
// vmcnt-tracked by the compiler (pipelines normally). coh is wave-uniform.
__device__ __forceinline__ f16x8 ldA(const f16* p, bool coh) {
  if (coh) {
    const u64* q = (const u64*)p;
    union { u64 v[2]; f16x8 h; } u;
    u.v[0] = __hip_atomic_load(q,     __ATOMIC_RELAXED, __HIP_MEMORY_SCOPE_AGENT);
    u.v[1] = __hip_atomic_load(q + 1, __ATOMIC_RELAXED, __HIP_MEMORY_SCOPE_AGENT);
    return u.h;
  }
  return *(const f16x8*)p;
}

#define MFMA16(A_, B_, C_) __builtin_amdgcn_mfma_f32_16x16x16f16(A_, B_, C_, 0, 0, 0)

// Decomposition (v6): WG (j,s) owns 64 rows x 64 gate-cols (16 hidden units x 4 gates).
// Wave wv: gate g = wv>>1 (16 cols), side kh = wv&1 (0: x@W, 1: h@U), full K=1024.
// Wr[32] f16x8 = 128 regs of weights; acc[4] f32x4 = 16; A-pipeline depth 3 = 48.
// 2-way LDS reduce (kh pairs), 32 KiB. 256 WGs -> all resident (r4-proven).
__global__ __launch_bounds__(512, 2) void k_main(const float* __restrict__ W,
                                                 const float* __restrict__ U,
                                                 const float* __restrict__ bias,
                                                 float* __restrict__ out) {
  const int j = blockIdx.x >> 6, s = blockIdx.x & 63;
  const int tid = threadIdx.x, lane = tid & 63, wv = tid >> 6;
  const int g = wv >> 1, kh = wv & 1;
  __shared__ float zl[8192];  // [8 waves][64 rows][16 cols], 32 KiB

  // ---- one-time weight gather f32 -> fp16 regs ----
  // Wr[kc] elem (hf*4+e): k = kc*32 + hf*16 + ((lane>>4)<<2) + e, col = g*1024 + s*16 + (lane&15)
  const float* src = (kh ? U : W) + (size_t)j * (HH * 4 * HH);
  const int col = g * 1024 + s * 16 + (lane & 15);
  const int krow = (lane >> 4) << 2;
  f16x8 Wr[32];
#pragma unroll
  for (int kc = 0; kc < 32; ++kc) {
    f16x8 v;
#pragma unroll
    for (int hf = 0; hf < 2; ++hf)
#pragma unroll
      for (int e = 0; e < 4; ++e)
        v[hf * 4 + e] = (f16)src[(size_t)(kc * 32 + hf * 16 + krow + e) * 4096 + col];
    Wr[kc] = v;
  }

  // ---- per-thread epilogue constants ----
  const int row = tid >> 3, hl0 = (tid & 7) * 2;
  const int hu0 = s * 16 + hl0;
  float br[2][4];
#pragma unroll
  for (int el = 0; el < 2; ++el)
#pragma unroll
    for (int gg = 0; gg < 4; ++gg) br[el][gg] = bias[j * 4096 + gg * 1024 + hu0 + el];
  const int fibase = ((((row >> 4) * 32 + (hu0 >> 5)) * 64 +
                       ((((hu0 >> 2) & 3) << 4) | (row & 15))) << 3) +
                     ((((hu0 >> 4) & 1) << 2) | (hu0 & 3));
  const int fib2 = fibase >> 1;  // u32 index (fibase even: hu0 even)
  unsigned* const hPub = (unsigned*)&g_h16[j][0][0];
  unsigned* const cPub = (unsigned*)&g_c16[j][0][0];
  float* c32p = &g_c32[j][row][hu0];
  const bool coh = kh || (j > 0);   // in16 is pre-launch constant -> plain loads ok

  for (int t = 0; t < TT; ++t) {
    // ---- WG-level dependency wait (NO cache fences) ----
    if (tid == 0) {
      if (j > 0) waitflag(&g_done[j - 1][t], NPROD);
      if (t > 0) waitflag(&g_done[j][t - 1], NPROD);
    }
    __syncthreads();
    asm volatile("" ::: "memory");

    const f16* Ab = kh ? &g_h16[j][t][0]
                       : (j ? &g_c16[j - 1][t + 1][0] : &g_in16[t][0]);

    // ---- GEMM: 64 rows x 16 cols (gate g), K=1024 of side kh ----
    f16x8 a[3][4];
#pragma unroll
    for (int pk = 0; pk < 2; ++pk)
#pragma unroll
      for (int rf = 0; rf < 4; ++rf)
        a[pk][rf] = ldA(Ab + (rf * 32 + pk) * 512 + lane * 8, coh);

    f32x4 acc[4];
#pragma unroll
    for (int rf = 0; rf < 4; ++rf) acc[rf] = (f32x4){0.f, 0.f, 0.f, 0.f};

#pragma unroll
    for (int kc = 0; kc < 32; ++kc) {
      if (kc < 30) {
#pragma unroll
        for (int rf = 0; rf < 4; ++rf)
          a[(kc + 2) % 3][rf] = ldA(Ab + (rf * 32 + kc + 2) * 512 + lane * 8, coh);
      }
      const f16x8 w8 = Wr[kc];
#pragma unroll
      for (int hf = 0; hf < 2; ++hf) {
        const f16x4 b4 = hf ? hi8(w8) : lo8(w8);
#pragma unroll
        for (int rf = 0; rf < 4; ++rf) {
          const f16x4 a4 = hf ? hi8(a[kc % 3][rf]) : lo8(a[kc % 3][rf]);
          acc[rf] = MFMA16(a4, b4, acc[rf]);
        }
      }
    }

    // ---- 2-way (kh) reduction via LDS ----
    __syncthreads();  // previous step's epilogue reads are done (end-of-loop barrier)
#pragma unroll
    for (int rf = 0; rf < 4; ++rf)
#pragma unroll
      for (int ri = 0; ri < 4; ++ri) {
        const int rr = rf * 16 + ((lane >> 4) << 2) + ri;
        zl[wv * 1024 + rr * 16 + (lane & 15)] = acc[rf][ri];
      }
    __syncthreads();

    // ---- epilogue: all 512 threads, 2 elements each ----
    float gsum[2][4];
#pragma unroll
    for (int gg = 0; gg < 4; ++gg) {
      const float2 p0 = *(const float2*)&zl[(gg * 2 + 0) * 1024 + row * 16 + hl0];
      const float2 p1 = *(const float2*)&zl[(gg * 2 + 1) * 1024 + row * 16 + hl0];
      gsum[0][gg] = p0.x + p1.x;
      gsum[1][gg] = p0.y + p1.y;
    }

    float cns[2], hns[2];
#pragma unroll
    for (int el = 0; el < 2; ++el) {
      const float zi = gsum[el][0] + br[el][0];
      const float zf = gsum[el][1] + br[el][1];
      const float zg = gsum[el][2] + br[el][2];
      const float zo = gsum[el][3] + br[el][3];
      const float cp = c32p[el];
      const float cn = sigf(zf) * cp + sigf(zi) * tanh_(zg);
      c32p[el] = cn;
      cns[el] = cn;
      hns[el] = sigf(zo) * tanh_(cn);
    }
    {
      union { f16 h[2]; unsigned u; } ph, pc;
      ph.h[0] = (f16)hns[0]; ph.h[1] = (f16)hns[1];
      __hip_atomic_store(hPub + (size_t)(t + 1) * 32768 + fib2, ph.u,
                         __ATOMIC_RELAXED, __HIP_MEMORY_SCOPE_AGENT);
      if (j < 3) {
        pc.h[0] = (f16)cns[0]; pc.h[1] = (f16)cns[1];
        __hip_atomic_store(cPub + (size_t)(t + 1) * 32768 + fib2, pc.u,
                           __ATOMIC_RELAXED, __HIP_MEMORY_SCOPE_AGENT);
      }
      if (j == 3 && t == TT - 1) {
        out[(row << 10) + hu0] = cns[0];
        out[(row << 10) + hu0 + 1] = cns[1];
      }
    }

    // ---- publish: drain device-scope stores, then flag (NO wbl2 fence) ----
    asm volatile("s_waitcnt vmcnt(0)" ::: "memory");
    __syncthreads();
    if (tid == 0)
      __hip_atomic_fetch_add(&g_done[j][t], 1u, __ATOMIC_RELAXED, __HIP_MEMORY_SCOPE_AGENT);
  }
}

extern "C" void kernel_launch(void* const* d_in, const int* in_sizes, int n_in,
                              void* d_out, int out_size, void* d_ws, size_t ws_size,
                              hipStream_t stream) {
  const float* inp  = (const float*)d_in[0];
  const float* W    = (const float*)d_in[1];
  const float* U    = (const float*)d_in[2];
  const float* bias = (const float*)d_in[3];
  float* out = (float*)d_out;
  k_init<<<256, 256, 0, stream>>>();
  k_pack_in<<<4096, 512, 0, stream>>>(inp);
  k_main<<<NWG, 512, 0, stream>>>(W, U, bias, out);
}

// Round 7
// 2489.746 us; speedup vs baseline: 5.4344x; 1.4674x over previous
//
#include <hip/hip_runtime.h>

#define TT 128
#define BB 64
#define HH 1024
#define LL 4
#define NWG 256
#define NPROD 64u

typedef _Float16 f16;
typedef __attribute__((ext_vector_type(4))) _Float16 f16x4;
typedef __attribute__((ext_vector_type(8))) _Float16 f16x8;
typedef __attribute__((ext_vector_type(4))) float f32x4;
typedef unsigned long long u64;

// ---------------- persistent device buffers ----------------
// Fragment layout for a [64 rows x 1024 k] fp16 tensor (HW-verified r1/r4/r6):
//   flat = ((rg*32 + ktp)*64 + lane)*8 + e
//   rg = row>>4, ktp = k>>5, lane = ((k>>2)&3)<<4 | (row&15), e = ((k>>4)&1)<<2 | (k&3)
// A-frag for v_mfma_f32_16x16x16f16: m = lane&15, k = 4*(lane>>4)+e
__device__ __align__(16) f16 g_in16[TT][65536];           // inputs, frag layout per t
// write-once state slots: slot t+1 holds post-step-t state. Producers publish with
// device-scope atomic stores; consumers read with device-scope atomic loads
// (bypass possibly-stale L1/L2). NO cache-wide fences anywhere (r6-proven).
__device__ __align__(16) f16 g_c16[LL][TT + 1][65536];    // cell state fp16 (feeds next layer)
__device__ __align__(16) f16 g_h16[LL][TT + 1][65536];    // hidden state fp16 (U-matmul input)
__device__ __align__(16) float g_c32[LL][BB][HH];         // cell state master f32 (WG-private)
__device__ unsigned g_done[LL][TT];                       // completion counters (64 WGs each)

// ---------------- init: zero state slot 0 + flags + c32 ----------------
__global__ void k_init() {
  unsigned tid = blockIdx.x * blockDim.x + threadIdx.x;
  unsigned n = gridDim.x * blockDim.x;
  float* c32 = &g_c32[0][0][0];
  for (unsigned i = tid; i < LL * BB * HH; i += n) c32[i] = 0.f;
  for (unsigned i = tid; i < LL * 65536 / 2; i += n) {
    int jj = i >> 15, q = i & 32767;
    ((unsigned*)&g_h16[jj][0][0])[q] = 0u;
  }
  unsigned* pd = &g_done[0][0];
  for (unsigned i = tid; i < LL * TT; i += n) pd[i] = 0u;
}

// ---------------- pack inputs f32 -> fp16 fragment layout (verified) ----------------
__global__ void k_pack_in(const float* __restrict__ inp) {
  int tid = blockIdx.x * blockDim.x + threadIdx.x;
  int t = tid >> 14, q = tid & 16383;
  int row = q >> 8, hu = (q & 255) << 2;
  const float4 x = *(const float4*)(inp + ((size_t)t << 16) + (row << 10) + hu);
  int rg = row >> 4, ktp = hu >> 5;
  int ln = (((hu >> 2) & 3) << 4) | (row & 15);
  int e0 = ((hu >> 4) & 1) << 2;
  f16x4 v = {(f16)x.x, (f16)x.y, (f16)x.z, (f16)x.w};
  *(f16x4*)&g_in16[t][(((rg * 32 + ktp) * 64 + ln) << 3) + e0] = v;
}

// ---------------- main persistent kernel ----------------
__device__ __forceinline__ float sigf(float x) { return 1.f / (1.f + __expf(-x)); }
__device__ __forceinline__ float tanh_(float x) {
  float q = __expf(-2.f * fabsf(x));
  return copysignf((1.f - q) / (1.f + q), x);
}
__device__ __forceinline__ f16x4 lo8(f16x8 v) { return __builtin_shufflevector(v, v, 0, 1, 2, 3); }
__device__ __forceinline__ f16x4 hi8(f16x8 v) { return __builtin_shufflevector(v, v, 4, 5, 6, 7); }
__device__ __forceinline__ void waitflag(const unsigned* p, unsigned n) {
  while (__hip_atomic_load(p, __ATOMIC_RELAXED, __HIP_MEMORY_SCOPE_AGENT) < n)
    __builtin_amdgcn_s_sleep(2);
}
// coherent (device-scope) 16B state load: two u64 atomic loads, bypass stale L1/L2,
// vmcnt-tracked by the compiler (pipelines normally). coh is wave-uniform. (r6-proven)
__device__ __forceinline__ f16x8 ldA(const f16* p, bool coh) {
  if (coh) {
    const u64* q = (const u64*)p;
    union { u64 v[2]; f16x8 h; } u;
    u.v[0] = __hip_atomic_load(q,     __ATOMIC_RELAXED, __HIP_MEMORY_SCOPE_AGENT);
    u.v[1] = __hip_atomic_load(q + 1, __ATOMIC_RELAXED, __HIP_MEMORY_SCOPE_AGENT);
    return u.h;
  }
  return *(const f16x8*)p;
}

#define MFMA16(A_, B_, C_) __builtin_amdgcn_mfma_f32_16x16x16f16(A_, B_, C_, 0, 0, 0)

// Decomposition (r4-proven, duplication-free): WG (j,s) owns 64 rows x 64 gate-cols
// (16 hidden units x 4 gates). Wave w: mat = w>>2 (0: x@W, 1: h@U), K-quarter kq = w&3
// -> holds B-frags for its 64 cols x 256 K in Wr[32] f16x8 (128 VGPR), loads a DISJOINT
// 32 KB A slice (no intra-WG duplication -> 256 KB unique coherent bytes/WG/step),
// computes full 64x64 partial z; 8 partials reduced via 64 KiB LDS (two col-phases).
// Sync (r6-proven): no fences; device-scope atomic loads/stores + vmcnt drain + flags.
__global__ __launch_bounds__(512, 2) void k_main(const float* __restrict__ W,
                                                 const float* __restrict__ U,
                                                 const float* __restrict__ bias,
                                                 float* __restrict__ out) {
  const int j = blockIdx.x >> 6, s = blockIdx.x & 63;
  const int tid = threadIdx.x, lane = tid & 63, wv = tid >> 6;
  const int mat = wv >> 2, kq = wv & 3;
  __shared__ float zl[16384];  // [8 waves][64 rows][32 colhalf], swizzled, 64 KiB

  // ---- one-time weight gather f32 -> fp16 regs (r4-verified) ----
  const float* src = (mat ? U : W) + (size_t)j * (HH * 4 * HH);
  const int colb = s * 16 + (lane & 15);
  const int kb0 = kq * 256 + ((lane >> 4) << 2);
  f16x8 Wr[32];
#pragma unroll
  for (int kk = 0; kk < 16; ++kk)
#pragma unroll
    for (int cfp = 0; cfp < 2; ++cfp) {
      f16x8 v;
#pragma unroll
      for (int hf = 0; hf < 2; ++hf)
#pragma unroll
        for (int e = 0; e < 4; ++e)
          v[hf * 4 + e] = (f16)src[(size_t)(kb0 + kk * 16 + e) * 4096 + (cfp * 2 + hf) * 1024 + colb];
      Wr[kk * 2 + cfp] = v;
    }

  // ---- per-thread epilogue constants (r4-verified) ----
  const int row = tid >> 3, hl0 = (tid & 7) * 2;
  const int hu0 = s * 16 + hl0;
  float br[2][4];
#pragma unroll
  for (int el = 0; el < 2; ++el)
#pragma unroll
    for (int g = 0; g < 4; ++g) br[el][g] = bias[j * 4096 + g * 1024 + hu0 + el];
  const int fibase = ((((row >> 4) * 32 + (hu0 >> 5)) * 64 +
                       ((((hu0 >> 2) & 3) << 4) | (row & 15))) << 3) +
                     ((((hu0 >> 4) & 1) << 2) | (hu0 & 3));
  const int fib2 = fibase >> 1;  // u32 index (fibase even: hu0 even)
  unsigned* const hPub = (unsigned*)&g_h16[j][0][0];
  unsigned* const cPub = (unsigned*)&g_c16[j][0][0];
  float* c32p = &g_c32[j][row][hu0];
  const int ktp0 = kq * 8;
  const bool coh = mat || (j > 0);  // in16 is pre-launch constant -> plain loads ok

  for (int t = 0; t < TT; ++t) {
    // ---- WG-level dependency wait (NO cache fences, r6-proven) ----
    if (tid == 0) {
      if (j > 0) waitflag(&g_done[j - 1][t], NPROD);
      if (t > 0) waitflag(&g_done[j][t - 1], NPROD);
    }
    __syncthreads();
    asm volatile("" ::: "memory");

    const f16* Ab = mat ? &g_h16[j][t][0]
                        : (j ? &g_c16[j - 1][t + 1][0] : &g_in16[t][0]);
    f16x8 a[2][4];
#pragma unroll
    for (int rf = 0; rf < 4; ++rf)
      a[0][rf] = ldA(Ab + (rf * 32 + ktp0) * 512 + lane * 8, coh);

    f32x4 acc[4][4];
#pragma unroll
    for (int rf = 0; rf < 4; ++rf)
#pragma unroll
      for (int cf = 0; cf < 4; ++cf) acc[rf][cf] = (f32x4){0.f, 0.f, 0.f, 0.f};

#pragma unroll
    for (int kc = 0; kc < 8; ++kc) {
      if (kc < 7) {
#pragma unroll
        for (int rf = 0; rf < 4; ++rf)
          a[(kc + 1) & 1][rf] = ldA(Ab + (rf * 32 + ktp0 + kc + 1) * 512 + lane * 8, coh);
      }
#pragma unroll
      for (int hf = 0; hf < 2; ++hf) {
        f16x4 a4[4];
#pragma unroll
        for (int rf = 0; rf < 4; ++rf)
          a4[rf] = hf ? hi8(a[kc & 1][rf]) : lo8(a[kc & 1][rf]);
#pragma unroll
        for (int cf = 0; cf < 4; ++cf) {
          const f16x8 wreg = Wr[(kc * 2 + hf) * 2 + (cf >> 1)];
          const f16x4 b4 = (cf & 1) ? hi8(wreg) : lo8(wreg);
#pragma unroll
          for (int rf = 0; rf < 4; ++rf) acc[rf][cf] = MFMA16(a4[rf], b4, acc[rf][cf]);
        }
      }
    }

    // ---- 8-wave reduction via 64 KiB LDS, two column-phases (r4-verified) ----
    float gsum[2][4];
#pragma unroll
    for (int P = 0; P < 2; ++P) {
      __syncthreads();  // also protects zl reuse vs previous phase/step
#pragma unroll
      for (int rf = 0; rf < 4; ++rf)
#pragma unroll
        for (int ch = 0; ch < 2; ++ch) {
          const int cf = P * 2 + ch;
#pragma unroll
          for (int ri = 0; ri < 4; ++ri) {
            const int rr = rf * 16 + ((lane >> 4) << 2) + ri;
            const int c2 = ch * 16 + (lane & 15);
            zl[wv * 2048 + rr * 32 + (c2 ^ ((rr & 4) << 2))] = acc[rf][cf][ri];
          }
        }
      __syncthreads();
#pragma unroll
      for (int ch = 0; ch < 2; ++ch) {
        const int idx = row * 32 + ((ch * 16 + hl0) ^ ((row & 4) << 2));
        float sx = 0.f, sy = 0.f;
#pragma unroll
        for (int w = 0; w < 8; ++w) {
          const float2 v = *(const float2*)&zl[w * 2048 + idx];
          sx += v.x; sy += v.y;
        }
        gsum[0][P * 2 + ch] = sx;
        gsum[1][P * 2 + ch] = sy;
      }
    }

    // ---- gates + state update (i,f,g,o) ----
    float cns[2], hns[2];
#pragma unroll
    for (int el = 0; el < 2; ++el) {
      const float zi = gsum[el][0] + br[el][0];
      const float zf = gsum[el][1] + br[el][1];
      const float zg = gsum[el][2] + br[el][2];
      const float zo = gsum[el][3] + br[el][3];
      const float cp = c32p[el];
      const float cn = sigf(zf) * cp + sigf(zi) * tanh_(zg);
      c32p[el] = cn;
      cns[el] = cn;
      hns[el] = sigf(zo) * tanh_(cn);
    }
    {
      union { f16 h[2]; unsigned u; } ph, pc;
      ph.h[0] = (f16)hns[0]; ph.h[1] = (f16)hns[1];
      __hip_atomic_store(hPub + (size_t)(t + 1) * 32768 + fib2, ph.u,
                         __ATOMIC_RELAXED, __HIP_MEMORY_SCOPE_AGENT);
      if (j < 3) {
        pc.h[0] = (f16)cns[0]; pc.h[1] = (f16)cns[1];
        __hip_atomic_store(cPub + (size_t)(t + 1) * 32768 + fib2, pc.u,
                           __ATOMIC_RELAXED, __HIP_MEMORY_SCOPE_AGENT);
      }
      if (j == 3 && t == TT - 1) {
        out[(row << 10) + hu0] = cns[0];
        out[(row << 10) + hu0 + 1] = cns[1];
      }
    }

    // ---- publish: drain device-scope stores, then flag (NO wbl2 fence, r6-proven) ----
    asm volatile("s_waitcnt vmcnt(0)" ::: "memory");
    __syncthreads();
    if (tid == 0)
      __hip_atomic_fetch_add(&g_done[j][t], 1u, __ATOMIC_RELAXED, __HIP_MEMORY_SCOPE_AGENT);
  }
}

extern "C" void kernel_launch(void* const* d_in, const int* in_sizes, int n_in,
                              void* d_out, int out_size, void* d_ws, size_t ws_size,
                              hipStream_t stream) {
  const float* inp  = (const float*)d_in[0];
  const float* W    = (const float*)d_in[1];
  const float* U    = (const float*)d_in[2];
  const float* bias = (const float*)d_in[3];
  float* out = (float*)d_out;
  k_init<<<256, 256, 0, stream>>>();
  k_pack_in<<<4096, 512, 0, stream>>>(inp);
  k_main<<<NWG, 512, 0, stream>>>(W, U, bias, out);
}